// Round 7
// baseline (757.455 us; speedup 1.0000x reference)
//
#include <hip/hip_runtime.h>

typedef float f32x4 __attribute__((ext_vector_type(4)));
typedef int   i32x4 __attribute__((ext_vector_type(4)));
typedef char  s8x16 __attribute__((ext_vector_type(16)));

#define GAS __attribute__((address_space(1)))
#define LAS __attribute__((address_space(3)))

constexpr int M = 8192;       // B*S
constexpr int N = 16384;      // D_OUT
constexpr int K = 4096;       // D_IN
constexpr long long NX = (long long)M * K;   // 33,554,432
constexpr long long NW = (long long)N * K;   // 67,108,864
constexpr int NPART = 2048;
constexpr int NKT = 32;       // K / 128

// ---------------- reductions ----------------

__global__ void reduce_absmax_kernel(const float* __restrict__ x,
                                     unsigned* __restrict__ gmax, int n4) {
  float m = 0.f;
  int stride = gridDim.x * blockDim.x;
  for (int i = blockIdx.x * blockDim.x + threadIdx.x; i < n4; i += stride) {
    f32x4 v = *(const f32x4*)(x + (size_t)i * 4);
    m = fmaxf(m, fmaxf(fmaxf(fabsf(v[0]), fabsf(v[1])),
                       fmaxf(fabsf(v[2]), fabsf(v[3]))));
  }
#pragma unroll
  for (int off = 32; off > 0; off >>= 1) m = fmaxf(m, __shfl_down(m, off));
  __shared__ float sm[4];
  int lane = threadIdx.x & 63, wid = threadIdx.x >> 6;
  if (lane == 0) sm[wid] = m;
  __syncthreads();
  if (threadIdx.x == 0) {
    m = fmaxf(fmaxf(sm[0], sm[1]), fmaxf(sm[2], sm[3]));
    atomicMax(gmax, __float_as_uint(m));  // |x| >= 0: bit-order == float-order
  }
}

__global__ void reduce_abssum_kernel(const float* __restrict__ w,
                                     float* __restrict__ partials, int n4) {
  float s = 0.f;
  int stride = gridDim.x * blockDim.x;
  for (int i = blockIdx.x * blockDim.x + threadIdx.x; i < n4; i += stride) {
    f32x4 v = *(const f32x4*)(w + (size_t)i * 4);
    s += fabsf(v[0]) + fabsf(v[1]) + fabsf(v[2]) + fabsf(v[3]);
  }
#pragma unroll
  for (int off = 32; off > 0; off >>= 1) s += __shfl_down(s, off);
  __shared__ float sm[4];
  int lane = threadIdx.x & 63, wid = threadIdx.x >> 6;
  if (lane == 0) sm[wid] = s;
  __syncthreads();
  if (threadIdx.x == 0) partials[blockIdx.x] = (sm[0] + sm[1]) + (sm[2] + sm[3]);
}

__global__ void finalize_kernel(const unsigned* __restrict__ gbits,
                                const float* __restrict__ partials,
                                float* __restrict__ params) {
  __shared__ double sd[256];
  double s = 0.0;
  for (int i = threadIdx.x; i < NPART; i += 256) s += (double)partials[i];
  sd[threadIdx.x] = s;
  __syncthreads();
  for (int h = 128; h > 0; h >>= 1) {
    if (threadIdx.x < h) sd[threadIdx.x] += sd[threadIdx.x + h];
    __syncthreads();
  }
  if (threadIdx.x == 0) {
    float beta  = fmaxf((float)(sd[0] / (double)NW), 1e-5f);
    float gamma = fmaxf(__uint_as_float(gbits[0]), 1e-5f);
    params[0] = 128.0f / gamma;          // activation scale (q/gamma)
    params[1] = beta;                    // weight divisor
    params[2] = beta * gamma / 128.0f;   // output rescale
  }
}

// ---------------- quantization (int8 outputs) ----------------

__global__ void quant_x_kernel(const float* __restrict__ x,
                               char* __restrict__ xq,
                               const float* __restrict__ params, int n16) {
  float s = params[0];
  int stride = gridDim.x * blockDim.x;
  for (int i = blockIdx.x * blockDim.x + threadIdx.x; i < n16; i += stride) {
    const f32x4* p = (const f32x4*)(x + (size_t)i * 16);
    s8x16 o;
#pragma unroll
    for (int v = 0; v < 4; ++v) {
      f32x4 t = p[v];
#pragma unroll
      for (int k = 0; k < 4; ++k) {
        float r = fminf(fmaxf(rintf(t[k] * s), -128.f), 127.f);
        o[v * 4 + k] = (char)(int)r;
      }
    }
    *(s8x16*)(xq + (size_t)i * 16) = o;
  }
}

__global__ void quant_w_kernel(const float* __restrict__ w,
                               char* __restrict__ wq,
                               const float* __restrict__ params, int n16) {
  float beta = params[1];
  int stride = gridDim.x * blockDim.x;
  for (int i = blockIdx.x * blockDim.x + threadIdx.x; i < n16; i += stride) {
    const f32x4* p = (const f32x4*)(w + (size_t)i * 16);
    s8x16 o;
#pragma unroll
    for (int v = 0; v < 4; ++v) {
      f32x4 t = p[v];
#pragma unroll
      for (int k = 0; k < 4; ++k) {
        // round_clip(|w|/beta, -1, 1): nonneg -> {0,1}; IEEE div matches ref rounding
        o[v * 4 + k] = (rintf(fabsf(t[k]) / beta) >= 1.0f) ? (char)1 : (char)0;
      }
    }
    *(s8x16*)(wq + (size_t)i * 16) = o;
  }
}

// ---------------- GEMM: m201-template port to i8 ----------------
// 256x256 tile, 8 waves (2m x 4n), per-wave 128x64, K-tile = 128 i8.
// LDS 2 x (A 32K + B 32K) = 128 KiB double-buffer.
// 4 phases per K-tile, 16 MFMA(16x16x64) each; reads/MFMA = 12/32 so the
// LDS pipe demand (~1156 cyc/CU-tile) < matrix pipe demand (~1306) — the
// binder rounds 5/6 hit (8 reads per 16 MFMA) is structurally removed.
// Staging 2 gloads/phase; tile T+1's pairs at P3(T-1),P0..P2(T); pair0 of
// T+2 at P3(T) then counted vmcnt(2) certifies T+1 (never drains to 0).
// Swizzle: LDS[row][s] = global[row][s ^ (row&7)], linear dest (rule #21).

#define SBAR __builtin_amdgcn_sched_barrier(0)

__global__ __launch_bounds__(512) void gemm_kernel(
    const char* __restrict__ A,   // xq int8 [M][K]
    const char* __restrict__ B,   // wq int8 [N][K]
    float* __restrict__ C,        // [M][N] fp32
    const float* __restrict__ params) {
  __shared__ __align__(16) char lds[131072];

  const int tid  = threadIdx.x;
  const int lane = tid & 63, wid = tid >> 6;
  const int wm = wid >> 2, wn = wid & 3;      // 2x4 waves, each 128x64
  const int r16 = lane & 15, q4 = lane >> 4;

  // T1: bijective XCD swizzle (2048 % 8 == 0), m-major chunks per XCD.
  const int wg = (blockIdx.x & 7) * 256 + (blockIdx.x >> 3);
  const int m0 = (wg >> 6) * 256, n0 = (wg & 63) * 256;

  // staging: one gload-instr = 8 rows x 128B; lane l -> row +(l>>3),
  // LDS slot l&7 (linear), global slot (l&7)^(row&7).
  const int csw = ((lane & 7) ^ ((lane >> 3) & 7)) * 16;
  const char* gA = A + (size_t)(m0 + wid * 32 + (lane >> 3)) * K + csw;
  const char* gB = B + (size_t)(n0 + wid * 32 + (lane >> 3)) * K + csw;
  const int dA = wid * 4096 + lane * 16;
  const int dB = 32768 + dA;

  auto stg = [&](int t, int q) {   // pair q (A+B, 8 rows each) of tile t
    char* L = lds + (t & 1) * 65536;
    const size_t go = (size_t)q * 8 * K + (size_t)t * 128;
    __builtin_amdgcn_global_load_lds((const GAS void*)(gA + go), (LAS void*)(L + dA + q * 1024), 16, 0, 0);
    __builtin_amdgcn_global_load_lds((const GAS void*)(gB + go), (LAS void*)(L + dB + q * 1024), 16, 0, 0);
  };

  // fragment reads: global slot g=kh*4+q4 of row -> LDS slot g^(row&7)
  const int abase = (wm * 128 + r16) * 128;
  const int bbase = 32768 + (wn * 64 + r16) * 128;
  const int sw0 = ((q4) ^ (r16 & 7)) * 16;
  const int sw1 = ((4 + q4) ^ (r16 & 7)) * 16;

  i32x4 acc[8][4] = {};
  i32x4 af[4][2], bf[4][2];

  // prologue: tile0 pairs 0-3, tile1 pair0; vmcnt(2) leaves tile1's pair.
  stg(0, 0); stg(0, 1); stg(0, 2); stg(0, 3);
  stg(1, 0);
  asm volatile("s_waitcnt vmcnt(2)" ::: "memory");
  SBAR; __builtin_amdgcn_s_barrier(); SBAR;

  for (int t = 0; t < NKT; ++t) {
    const char* buf = lds + (t & 1) * 65536;
    // ---- P0: read A[0..3]+B[0..1] (12), stage pair1(T+1) ----
#pragma unroll
    for (int i = 0; i < 4; ++i) {
      af[i][0] = *(const i32x4*)(buf + abase + i * 2048 + sw0);
      af[i][1] = *(const i32x4*)(buf + abase + i * 2048 + sw1);
    }
#pragma unroll
    for (int j = 0; j < 2; ++j) {
      bf[j][0] = *(const i32x4*)(buf + bbase + j * 2048 + sw0);
      bf[j][1] = *(const i32x4*)(buf + bbase + j * 2048 + sw1);
    }
    if (t + 1 < NKT) stg(t + 1, 1);
    SBAR; __builtin_amdgcn_s_barrier(); SBAR;
    asm volatile("s_waitcnt lgkmcnt(0)" ::: "memory"); SBAR;
    __builtin_amdgcn_s_setprio(1);
#pragma unroll
    for (int kh = 0; kh < 2; ++kh)
#pragma unroll
      for (int i = 0; i < 4; ++i)
#pragma unroll
        for (int j = 0; j < 2; ++j)
          acc[i][j] = __builtin_amdgcn_mfma_i32_16x16x64_i8(af[i][kh], bf[j][kh], acc[i][j], 0, 0, 0);
    __builtin_amdgcn_s_setprio(0);
    SBAR; __builtin_amdgcn_s_barrier(); SBAR;
    // ---- P1: read B[2..3] (4), stage pair2(T+1) ----
#pragma unroll
    for (int j = 2; j < 4; ++j) {
      bf[j][0] = *(const i32x4*)(buf + bbase + j * 2048 + sw0);
      bf[j][1] = *(const i32x4*)(buf + bbase + j * 2048 + sw1);
    }
    if (t + 1 < NKT) stg(t + 1, 2);
    SBAR; __builtin_amdgcn_s_barrier(); SBAR;
    asm volatile("s_waitcnt lgkmcnt(0)" ::: "memory"); SBAR;
    __builtin_amdgcn_s_setprio(1);
#pragma unroll
    for (int kh = 0; kh < 2; ++kh)
#pragma unroll
      for (int i = 0; i < 4; ++i)
#pragma unroll
        for (int j = 2; j < 4; ++j)
          acc[i][j] = __builtin_amdgcn_mfma_i32_16x16x64_i8(af[i][kh], bf[j][kh], acc[i][j], 0, 0, 0);
    __builtin_amdgcn_s_setprio(0);
    SBAR; __builtin_amdgcn_s_barrier(); SBAR;
    // ---- P2: read A[4..7] (8), stage pair3(T+1) ----
#pragma unroll
    for (int i = 0; i < 4; ++i) {
      af[i][0] = *(const i32x4*)(buf + abase + (i + 4) * 2048 + sw0);
      af[i][1] = *(const i32x4*)(buf + abase + (i + 4) * 2048 + sw1);
    }
    if (t + 1 < NKT) stg(t + 1, 3);
    SBAR; __builtin_amdgcn_s_barrier(); SBAR;
    asm volatile("s_waitcnt lgkmcnt(0)" ::: "memory"); SBAR;
    __builtin_amdgcn_s_setprio(1);
#pragma unroll
    for (int kh = 0; kh < 2; ++kh)
#pragma unroll
      for (int i = 0; i < 4; ++i)
#pragma unroll
        for (int j = 0; j < 2; ++j)
          acc[i + 4][j] = __builtin_amdgcn_mfma_i32_16x16x64_i8(af[i][kh], bf[j][kh], acc[i + 4][j], 0, 0, 0);
    __builtin_amdgcn_s_setprio(0);
    SBAR; __builtin_amdgcn_s_barrier(); SBAR;
    // ---- P3: no reads; stage pair0(T+2) into buf[t&1] (tile-t reads all
    // retired at P2's lgkm + bar); counted vmcnt certifies tile T+1 ----
    if (t + 2 < NKT) stg(t + 2, 0);
    if (t < NKT - 2) {
      asm volatile("s_waitcnt vmcnt(2)" ::: "memory");   // leaves T+2's pair0
    } else {
      asm volatile("s_waitcnt vmcnt(0)" ::: "memory");
    }
    SBAR; __builtin_amdgcn_s_barrier(); SBAR;
    __builtin_amdgcn_s_setprio(1);
#pragma unroll
    for (int kh = 0; kh < 2; ++kh)
#pragma unroll
      for (int i = 0; i < 4; ++i)
#pragma unroll
        for (int j = 2; j < 4; ++j)
          acc[i + 4][j] = __builtin_amdgcn_mfma_i32_16x16x64_i8(af[i][kh], bf[j][kh], acc[i + 4][j], 0, 0, 0);
    __builtin_amdgcn_s_setprio(0);
    SBAR; __builtin_amdgcn_s_barrier(); SBAR;
  }

  // epilogue: C/D layout (m89-verified): col = lane&15, row = (lane>>4)*4+reg
  const float sc = params[2];
  const int crow = m0 + wm * 128 + q4 * 4;
  const int ccol = n0 + wn * 64 + r16;
#pragma unroll
  for (int i = 0; i < 8; ++i)
#pragma unroll
    for (int j = 0; j < 4; ++j)
#pragma unroll
      for (int r = 0; r < 4; ++r)
        C[(size_t)(crow + i * 16 + r) * N + (ccol + j * 16)] = (float)acc[i][j][r] * sc;
}

// ---------------- launch ----------------

extern "C" void kernel_launch(void* const* d_in, const int* in_sizes, int n_in,
                              void* d_out, int out_size, void* d_ws, size_t ws_size,
                              hipStream_t stream) {
  const float* x = (const float*)d_in[0];
  const float* w = (const float*)d_in[1];
  float* out = (float*)d_out;
  char* ws = (char*)d_ws;

  unsigned* gamma_bits = (unsigned*)ws;            // 4 B
  float*    params     = (float*)(ws + 16);        // 3 floats
  float*    partials   = (float*)(ws + 256);       // 2048 floats
  char*     xq = ws + 16384;                       // 33,554,432 B
  char*     wq = ws + 16384 + (size_t)NX;          // 67,108,864 B

  hipMemsetAsync(ws, 0, 256, stream);  // zero gamma accumulator each call

  reduce_absmax_kernel<<<NPART, 256, 0, stream>>>(x, gamma_bits, (int)(NX / 4));
  reduce_abssum_kernel<<<NPART, 256, 0, stream>>>(w, partials, (int)(NW / 4));
  finalize_kernel<<<1, 256, 0, stream>>>(gamma_bits, partials, params);
  quant_x_kernel<<<2048, 256, 0, stream>>>(x, xq, params, (int)(NX / 16));
  quant_w_kernel<<<2048, 256, 0, stream>>>(w, wq, params, (int)(NW / 16));

  gemm_kernel<<<2048, 512, 0, stream>>>(xq, wq, out, params);
}